// Round 4
// baseline (733.531 us; speedup 1.0000x reference)
//
#include <hip/hip_runtime.h>

#define GRID_DIM 132
#define SLAB (GRID_DIM * GRID_DIM)   // 17424
#define NB 512                       // 8x8x8 bins, each 16^3 in int(t) space
#define REG 20                       // staged region edge (16 + 3 taps + 1 slack)
#define REG3 (REG * REG * REG)       // 8000 floats = 32 KB

__device__ __forceinline__ void bspline_w(float x, float w[4]) {
    float omx = 1.0f - x;
    w[0] = omx * omx * omx * (1.0f / 6.0f);
    w[1] = (3.0f * (x - 2.0f) * x * x + 4.0f) * (1.0f / 6.0f);
    w[2] = (-3.0f * omx * omx * (x + 1.0f) + 4.0f) * (1.0f / 6.0f);
    w[3] = x * x * x * (1.0f / 6.0f);
}

// bin id, x-major (sorted order sweeps x-slabs)
__device__ __forceinline__ int calc_bin(float tx, float ty, float tz) {
    int bx = min(7, ((int)tx - 1) >> 4);
    int by = min(7, ((int)ty - 1) >> 4);
    int bz = min(7, ((int)tz - 1) >> 4);
    return (bx << 6) | (by << 3) | bz;
}

__device__ __forceinline__ void load_pt(const float* __restrict__ pts, int i,
                                        float& tx, float& ty, float& tz, bool& inb) {
    tx = pts[3 * i + 0] + 1.0f;   // ORIGIN = -(1+1e-8) == -1.0f in fp32, STEP = 1
    ty = pts[3 * i + 1] + 1.0f;
    tz = pts[3 * i + 2] + 1.0f;
    inb = (tx >= 1.0f) && (ty >= 1.0f) && (tz >= 1.0f) &&
          (tx < 130.0f) && (ty < 130.0f) && (tz < 130.0f);
    if (!inb) { tx = ty = tz = 1.0f; }
}

__global__ __launch_bounds__(256) void hist_kernel(
    const float* __restrict__ pts, int n, unsigned* __restrict__ hist)
{
    __shared__ unsigned lh[NB];
    for (int b = threadIdx.x; b < NB; b += 256) lh[b] = 0u;
    __syncthreads();
    for (int i = blockIdx.x * blockDim.x + threadIdx.x; i < n;
         i += gridDim.x * blockDim.x) {
        float tx, ty, tz; bool inb;
        load_pt(pts, i, tx, ty, tz, inb);
        atomicAdd(&lh[calc_bin(tx, ty, tz)], 1u);
    }
    __syncthreads();
    for (int b = threadIdx.x; b < NB; b += 256)
        if (lh[b]) atomicAdd(&hist[b], lh[b]);
}

// Exclusive scan of 512 bin counts -> bin_start[513] and working cursors gcur[512].
__global__ __launch_bounds__(256) void scan_kernel(
    const unsigned* __restrict__ hist, unsigned* __restrict__ bin_start,
    unsigned* __restrict__ gcur)
{
    __shared__ unsigned sc[256];
    int t = threadIdx.x;
    unsigned a = hist[2 * t], b = hist[2 * t + 1];
    sc[t] = a + b;
    __syncthreads();
    for (int off = 1; off < 256; off <<= 1) {
        unsigned v = (t >= off) ? sc[t - off] : 0u;
        __syncthreads();
        sc[t] += v;
        __syncthreads();
    }
    unsigned base = (t == 0) ? 0u : sc[t - 1];
    bin_start[2 * t] = base;         gcur[2 * t] = base;
    bin_start[2 * t + 1] = base + a; gcur[2 * t + 1] = base + a;
    if (t == 255) bin_start[NB] = sc[255];
}

// Proven round-2 scatter, plus a DENSE inverse-permutation write (inv[i] = pos).
__global__ __launch_bounds__(256) void scatter_kernel(
    const float* __restrict__ pts, int n, unsigned* __restrict__ gcur,
    float4* __restrict__ sorted, unsigned* __restrict__ inv)
{
    int i = blockIdx.x * blockDim.x + threadIdx.x;
    if (i >= n) return;
    float tx, ty, tz; bool inb;
    load_pt(pts, i, tx, ty, tz, inb);
    int bin = calc_bin(tx, ty, tz);
    unsigned pos = atomicAdd(&gcur[bin], 1u);
    unsigned tag = (unsigned)i | (inb ? 0u : 0x80000000u);
    sorted[pos] = make_float4(tx, ty, tz, __uint_as_float(tag));
    inv[i] = pos;                     // dense, coalesced
}

// One block per (bin, half): stage the bin's 20^3 grid region in LDS, evaluate
// its points from the sorted array, write values DENSE by sorted position.
__global__ __launch_bounds__(256) void eval_kernel(
    const float4* __restrict__ sorted, const float* __restrict__ cp,
    const unsigned* __restrict__ bin_start, float* __restrict__ val_s)
{
    __shared__ float region[REG3];   // 32 KB

    // bijective XCD swizzle: 1024 blocks, 8 XCDs -> each XCD a contiguous x-slab
    int bid = blockIdx.x;
    int wg = (bid & 7) * 128 + (bid >> 3);
    int bin = wg >> 1, half = wg & 1;
    int x0 = (bin >> 6) << 4, y0 = ((bin >> 3) & 7) << 4, z0 = (bin & 7) << 4;

    const float* src = cp + (size_t)x0 * SLAB + y0 * GRID_DIM + z0;
    for (int v = threadIdx.x; v < REG3; v += 256) {
        int gx = v / (REG * REG);
        int r = v - gx * (REG * REG);
        int gy = r / REG;
        int gz = r - gy * REG;
        region[v] = src[gx * SLAB + gy * GRID_DIM + gz];
    }
    __syncthreads();

    unsigned s = bin_start[bin], e = bin_start[bin + 1];
    unsigned hlen = (e - s) >> 1;
    unsigned i0 = s + hlen * half;
    unsigned i1 = half ? e : s + hlen;

    for (unsigned i = i0 + threadIdx.x; i < i1; i += 256) {
        float4 p = sorted[i];
        unsigned tag = __float_as_uint(p.w);
        int ix = (int)p.x, iy = (int)p.y, iz = (int)p.z;
        float wx[4], wy[4], wz[4];
        bspline_w(p.x - (float)ix, wx);
        bspline_w(p.y - (float)iy, wy);
        bspline_w(p.z - (float)iz, wz);
        int lx = ix - 1 - x0, ly = iy - 1 - y0, lz = iz - 1 - z0;
        const float* rb = region + (lx * REG + ly) * REG + lz;
        float acc = 0.0f;
#pragma unroll
        for (int a = 0; a < 4; ++a) {
            float accy = 0.0f;
#pragma unroll
            for (int b = 0; b < 4; ++b) {
                const float* row = rb + (a * REG + b) * REG;
                float sz = fmaf(row[0], wz[0], fmaf(row[1], wz[1],
                           fmaf(row[2], wz[2], row[3] * wz[3])));
                accy = fmaf(wy[b], sz, accy);
            }
            acc = fmaf(wx[a], accy, acc);
        }
        val_s[i] = (tag >> 31) ? 0.0f : acc;
    }
}

// out[i] = val_s[inv[i]] : dense reads of inv, random 4B READS of L2/L3-resident
// val_s (cheap), dense writes of out.
__global__ __launch_bounds__(256) void unscatter_kernel(
    const float* __restrict__ val_s, const unsigned* __restrict__ inv,
    float* __restrict__ out, int n)
{
    int g = blockIdx.x * blockDim.x + threadIdx.x;
    int base = g * 4;
    if (base + 3 < n) {
        uint4 iv = ((const uint4*)inv)[g];
        float4 o;
        o.x = val_s[iv.x]; o.y = val_s[iv.y]; o.z = val_s[iv.z]; o.w = val_s[iv.w];
        ((float4*)out)[g] = o;
    } else if (base < n) {
        for (int k = base; k < n; ++k) out[k] = val_s[inv[k]];
    }
}

// Fallback (round-1 kernel) if ws_size is insufficient.
__global__ __launch_bounds__(256) void eval_unsorted_kernel(
    const float* __restrict__ pts, const float* __restrict__ cp,
    float* __restrict__ out, int n)
{
    int i = blockIdx.x * blockDim.x + threadIdx.x;
    if (i >= n) return;
    float tx, ty, tz; bool inb;
    load_pt(pts, i, tx, ty, tz, inb);
    int ix = (int)tx, iy = (int)ty, iz = (int)tz;
    float wx[4], wy[4], wz[4];
    bspline_w(tx - (float)ix, wx);
    bspline_w(ty - (float)iy, wy);
    bspline_w(tz - (float)iz, wz);
    const float* bse = cp + (size_t)(ix - 1) * SLAB + (size_t)(iy - 1) * GRID_DIM + (iz - 1);
    float acc = 0.0f;
#pragma unroll
    for (int a = 0; a < 4; ++a) {
        float accy = 0.0f;
#pragma unroll
        for (int b = 0; b < 4; ++b) {
            const float* row = bse + a * SLAB + b * GRID_DIM;
            float4 v;
            __builtin_memcpy(&v, row, 16);
            float sz = fmaf(v.x, wz[0], fmaf(v.y, wz[1], fmaf(v.z, wz[2], v.w * wz[3])));
            accy = fmaf(wy[b], sz, accy);
        }
        acc = fmaf(wx[a], accy, acc);
    }
    out[i] = inb ? acc : 0.0f;
}

extern "C" void kernel_launch(void* const* d_in, const int* in_sizes, int n_in,
                              void* d_out, int out_size, void* d_ws, size_t ws_size,
                              hipStream_t stream) {
    const float* pts = (const float*)d_in[0];      // (N, 3) fp32
    const float* cp  = (const float*)d_in[1];      // (1, 132, 132, 132) fp32
    float* out       = (float*)d_out;              // (N, 1) fp32

    int n = in_sizes[0] / 3;                       // 2,000,000

    // ws layout: hist[512] @0 | bin_start[513] @4096 | gcur[512] @8192 |
    //            sorted float4[n] @65536 | inv u32[n] | val_s float[n]
    size_t off_sorted = 65536;
    size_t off_inv    = off_sorted + (size_t)n * sizeof(float4);
    size_t off_val    = off_inv    + (size_t)n * sizeof(unsigned);
    size_t need       = off_val    + (size_t)n * sizeof(float);

    if (ws_size >= need) {
        unsigned* hist      = (unsigned*)d_ws;
        unsigned* bin_start = (unsigned*)((char*)d_ws + 4096);
        unsigned* gcur      = (unsigned*)((char*)d_ws + 8192);
        float4*   sorted    = (float4*)((char*)d_ws + off_sorted);
        unsigned* inv       = (unsigned*)((char*)d_ws + off_inv);
        float*    val_s     = (float*)((char*)d_ws + off_val);

        int nwg = (n + 255) / 256;
        int uwg = ((n + 3) / 4 + 255) / 256;

        hipMemsetAsync(hist, 0, NB * sizeof(unsigned), stream);
        hipLaunchKernelGGL(hist_kernel, dim3(512), dim3(256), 0, stream, pts, n, hist);
        hipLaunchKernelGGL(scan_kernel, dim3(1), dim3(256), 0, stream, hist, bin_start, gcur);
        hipLaunchKernelGGL(scatter_kernel, dim3(nwg), dim3(256), 0, stream,
                           pts, n, gcur, sorted, inv);
        hipLaunchKernelGGL(eval_kernel, dim3(NB * 2), dim3(256), 0, stream,
                           sorted, cp, bin_start, val_s);
        hipLaunchKernelGGL(unscatter_kernel, dim3(uwg), dim3(256), 0, stream,
                           val_s, inv, out, n);
    } else {
        hipLaunchKernelGGL(eval_unsorted_kernel, dim3((n + 255) / 256), dim3(256), 0, stream,
                           pts, cp, out, n);
    }
}

// Round 5
// 244.728 us; speedup vs baseline: 2.9973x; 2.9973x over previous
//
#include <hip/hip_runtime.h>

#define GRID_DIM 132
#define SLAB (GRID_DIM * GRID_DIM)   // 17424
#define NSLAB 8                      // 8 x-slabs, width 16 in int(t) space
#define CHUNK 2048                   // points per partition block
#define KPT (CHUNK / 256)            // 8 points per thread
#define MAXBLK 1020                  // header-buffer capacity guard

__device__ __forceinline__ void bspline_w(float x, float w[4]) {
    float omx = 1.0f - x;
    w[0] = omx * omx * omx * (1.0f / 6.0f);
    w[1] = (3.0f * (x - 2.0f) * x * x + 4.0f) * (1.0f / 6.0f);
    w[2] = (-3.0f * omx * omx * (x + 1.0f) + 4.0f) * (1.0f / 6.0f);
    w[3] = x * x * x * (1.0f / 6.0f);
}

__device__ __forceinline__ void load_pt(const float* __restrict__ pts, int i,
                                        float& tx, float& ty, float& tz, bool& inb) {
    tx = pts[3 * i + 0] + 1.0f;   // ORIGIN = -(1+1e-8) == -1.0f in fp32, STEP = 1
    ty = pts[3 * i + 1] + 1.0f;
    tz = pts[3 * i + 2] + 1.0f;
    inb = (tx >= 1.0f) && (ty >= 1.0f) && (tz >= 1.0f) &&
          (tx < 130.0f) && (ty < 130.0f) && (tz < 130.0f);
    if (!inb) { tx = ty = tz = 1.0f; }
}

__device__ __forceinline__ int slab_of(float tx) {
    return min(7, ((int)tx - 1) >> 4);
}

// Per-chunk 8-bin histogram -> blockhist[bin*nblk + blk]. No global atomics.
__global__ __launch_bounds__(256) void hist8_kernel(
    const float* __restrict__ pts, int n, int nblk, unsigned* __restrict__ bh)
{
    __shared__ unsigned lc[NSLAB];
    int tid = threadIdx.x, blk = blockIdx.x;
    int c0 = blk * CHUNK;
    if (tid < NSLAB) lc[tid] = 0u;
    __syncthreads();
#pragma unroll
    for (int k = 0; k < KPT; ++k) {
        int i = c0 + tid + k * 256;
        if (i < n) {
            float tx, ty, tz; bool inb;
            load_pt(pts, i, tx, ty, tz, inb);
            atomicAdd(&lc[slab_of(tx)], 1u);
        }
    }
    __syncthreads();
    if (tid < NSLAB) bh[tid * nblk + blk] = lc[tid];
}

// Single-block exclusive scan of all 8*nblk counts (bin-major, block-minor)
// -> segstart[] (absolute offsets) and slabstart[0..8]. Fully deterministic.
__global__ __launch_bounds__(256) void scan8_kernel(
    const unsigned* __restrict__ bh, unsigned* __restrict__ segstart,
    unsigned* __restrict__ slabstart, int nblk, int n)
{
    __shared__ unsigned sc[256];
    __shared__ unsigned slabBnd[NSLAB];
    int t = threadIdx.x;
    int TOT = NSLAB * nblk;          // <= 8160 (nblk <= MAXBLK)

    unsigned local[32];
    unsigned s = 0;
#pragma unroll
    for (int j = 0; j < 32; ++j) {
        int idx = t * 32 + j;
        unsigned v = (idx < TOT) ? bh[idx] : 0u;
        local[j] = v; s += v;
    }
    sc[t] = s;
    __syncthreads();
    for (int off = 1; off < 256; off <<= 1) {
        unsigned v = (t >= off) ? sc[t - off] : 0u;
        __syncthreads();
        sc[t] += v;
        __syncthreads();
    }
    unsigned base = (t == 0) ? 0u : sc[t - 1];
#pragma unroll
    for (int j = 0; j < 32; ++j) {
        int idx = t * 32 + j;
        if (idx < TOT) {
            if ((idx % nblk) == 0) slabBnd[idx / nblk] = base;
            segstart[idx] = base;
            base += local[j];
        }
    }
    __syncthreads();
    if (t < NSLAB) slabstart[t] = slabBnd[t];
    if (t == NSLAB) slabstart[NSLAB] = (unsigned)n;
}

// Deterministic partition: points held in registers, ordered by slab in LDS,
// written out in contiguous per-(block,slab) runs (~4KB bursts). inv[] writes
// confined to this chunk's 8KB window. No global atomics anywhere.
__global__ __launch_bounds__(256) void partition_kernel(
    const float* __restrict__ pts, int n, int nblk,
    const unsigned* __restrict__ segstart,
    float4* __restrict__ sorted, unsigned* __restrict__ inv)
{
    __shared__ float4 buf[CHUNK];                       // 32 KB
    __shared__ unsigned lcnt[NSLAB], lstart[NSLAB], lcur[NSLAB], gseg[NSLAB];
    int tid = threadIdx.x, blk = blockIdx.x;
    int c0 = blk * CHUNK;
    int m = min(n - c0, CHUNK);

    if (tid < NSLAB) lcnt[tid] = 0u;
    __syncthreads();

    float4 pv[KPT];
    int bins[KPT];
#pragma unroll
    for (int k = 0; k < KPT; ++k) {
        int i = c0 + tid + k * 256;
        bins[k] = -1;
        if (i < n) {
            float tx, ty, tz; bool inb;
            load_pt(pts, i, tx, ty, tz, inb);
            unsigned tag = (unsigned)i | (inb ? 0u : 0x80000000u);
            pv[k] = make_float4(tx, ty, tz, __uint_as_float(tag));
            bins[k] = slab_of(tx);
            atomicAdd(&lcnt[bins[k]], 1u);
        }
    }
    __syncthreads();

    if (tid == 0) {
        unsigned run = 0;
        for (int b = 0; b < NSLAB; ++b) { lstart[b] = run; run += lcnt[b]; }
    }
    __syncthreads();
    if (tid < NSLAB) { lcur[tid] = lstart[tid]; gseg[tid] = segstart[tid * nblk + blk]; }
    __syncthreads();

#pragma unroll
    for (int k = 0; k < KPT; ++k) {
        if (bins[k] >= 0) {
            unsigned pos = atomicAdd(&lcur[bins[k]], 1u);
            buf[pos] = pv[k];
        }
    }
    __syncthreads();

    for (int j = tid; j < m; j += 256) {
        float4 p = buf[j];
        int b = slab_of(p.x);
        unsigned g = gseg[b] + ((unsigned)j - lstart[b]);
        sorted[g] = p;
        inv[__float_as_uint(p.w) & 0x7fffffffu] = g;
    }
}

// One slab per XCD (slab = bid&7): per-XCD grid working set 20 planes = 1.4MB
// fits its L2, so gathers are L2 hits. Coalesced sorted reads, dense val_s.
__global__ __launch_bounds__(256) void eval_kernel(
    const float4* __restrict__ sorted, const float* __restrict__ cp,
    const unsigned* __restrict__ slabstart, float* __restrict__ val_s)
{
    int bid = blockIdx.x;
    int s = bid & 7, sub = bid >> 3;    // 1024 blocks -> 128 sub-blocks per slab
    unsigned start = slabstart[s], end = slabstart[s + 1];

    for (unsigned i = start + (unsigned)sub * 256u + threadIdx.x; i < end;
         i += 128u * 256u) {
        float4 p = sorted[i];
        unsigned tag = __float_as_uint(p.w);
        int ix = (int)p.x, iy = (int)p.y, iz = (int)p.z;
        float wx[4], wy[4], wz[4];
        bspline_w(p.x - (float)ix, wx);
        bspline_w(p.y - (float)iy, wy);
        bspline_w(p.z - (float)iz, wz);
        const float* base = cp + (size_t)(ix - 1) * SLAB + (size_t)(iy - 1) * GRID_DIM + (iz - 1);
        float acc = 0.0f;
#pragma unroll
        for (int a = 0; a < 4; ++a) {
            float accy = 0.0f;
#pragma unroll
            for (int b = 0; b < 4; ++b) {
                const float* row = base + a * SLAB + b * GRID_DIM;
                float4 v;
                __builtin_memcpy(&v, row, 16);
                float sz = fmaf(v.x, wz[0], fmaf(v.y, wz[1], fmaf(v.z, wz[2], v.w * wz[3])));
                accy = fmaf(wy[b], sz, accy);
            }
            acc = fmaf(wx[a], accy, acc);
        }
        val_s[i] = (tag >> 31) ? 0.0f : acc;
    }
}

// out[i] = val_s[inv[i]] : dense inv reads, random 4B READS of cached val_s,
// dense out writes. (Proven in round 4.)
__global__ __launch_bounds__(256) void unscatter_kernel(
    const float* __restrict__ val_s, const unsigned* __restrict__ inv,
    float* __restrict__ out, int n)
{
    int g = blockIdx.x * blockDim.x + threadIdx.x;
    int base = g * 4;
    if (base + 3 < n) {
        uint4 iv = ((const uint4*)inv)[g];
        float4 o;
        o.x = val_s[iv.x]; o.y = val_s[iv.y]; o.z = val_s[iv.z]; o.w = val_s[iv.w];
        ((float4*)out)[g] = o;
    } else if (base < n) {
        for (int k = base; k < n; ++k) out[k] = val_s[inv[k]];
    }
}

// Fallback (round-1 proven) if ws/config insufficient.
__global__ __launch_bounds__(256) void eval_unsorted_kernel(
    const float* __restrict__ pts, const float* __restrict__ cp,
    float* __restrict__ out, int n)
{
    int i = blockIdx.x * blockDim.x + threadIdx.x;
    if (i >= n) return;
    float tx, ty, tz; bool inb;
    load_pt(pts, i, tx, ty, tz, inb);
    int ix = (int)tx, iy = (int)ty, iz = (int)tz;
    float wx[4], wy[4], wz[4];
    bspline_w(tx - (float)ix, wx);
    bspline_w(ty - (float)iy, wy);
    bspline_w(tz - (float)iz, wz);
    const float* bse = cp + (size_t)(ix - 1) * SLAB + (size_t)(iy - 1) * GRID_DIM + (iz - 1);
    float acc = 0.0f;
#pragma unroll
    for (int a = 0; a < 4; ++a) {
        float accy = 0.0f;
#pragma unroll
        for (int b = 0; b < 4; ++b) {
            const float* row = bse + a * SLAB + b * GRID_DIM;
            float4 v;
            __builtin_memcpy(&v, row, 16);
            float sz = fmaf(v.x, wz[0], fmaf(v.y, wz[1], fmaf(v.z, wz[2], v.w * wz[3])));
            accy = fmaf(wy[b], sz, accy);
        }
        acc = fmaf(wx[a], accy, acc);
    }
    out[i] = inb ? acc : 0.0f;
}

extern "C" void kernel_launch(void* const* d_in, const int* in_sizes, int n_in,
                              void* d_out, int out_size, void* d_ws, size_t ws_size,
                              hipStream_t stream) {
    const float* pts = (const float*)d_in[0];      // (N, 3) fp32
    const float* cp  = (const float*)d_in[1];      // (1, 132, 132, 132) fp32
    float* out       = (float*)d_out;              // (N, 1) fp32

    int n = in_sizes[0] / 3;                       // 2,000,000
    int nblk = (n + CHUNK - 1) / CHUNK;            // 977

    // ws header (64KB total): blockhist @0 (<=32KB) | segstart @32768 (<=~32KB)
    //                         slabstart @65536-64 (9 u32, above segstart's use)
    // payload: sorted float4[n] @65536 | inv u32[n] | val_s float[n]
    size_t off_sorted = 65536;
    size_t off_inv    = off_sorted + (size_t)n * sizeof(float4);
    size_t off_val    = off_inv    + (size_t)n * sizeof(unsigned);
    size_t need       = off_val    + (size_t)n * sizeof(float);

    if (ws_size >= need && nblk <= MAXBLK) {
        unsigned* bh        = (unsigned*)d_ws;
        unsigned* segstart  = (unsigned*)((char*)d_ws + 32768);
        unsigned* slabstart = (unsigned*)((char*)d_ws + 65536 - 64);
        float4*   sorted    = (float4*)((char*)d_ws + off_sorted);
        unsigned* inv       = (unsigned*)((char*)d_ws + off_inv);
        float*    val_s     = (float*)((char*)d_ws + off_val);

        int uwg = ((n + 3) / 4 + 255) / 256;

        hipLaunchKernelGGL(hist8_kernel, dim3(nblk), dim3(256), 0, stream,
                           pts, n, nblk, bh);
        hipLaunchKernelGGL(scan8_kernel, dim3(1), dim3(256), 0, stream,
                           bh, segstart, slabstart, nblk, n);
        hipLaunchKernelGGL(partition_kernel, dim3(nblk), dim3(256), 0, stream,
                           pts, n, nblk, segstart, sorted, inv);
        hipLaunchKernelGGL(eval_kernel, dim3(1024), dim3(256), 0, stream,
                           sorted, cp, slabstart, val_s);
        hipLaunchKernelGGL(unscatter_kernel, dim3(uwg), dim3(256), 0, stream,
                           val_s, inv, out, n);
    } else {
        hipLaunchKernelGGL(eval_unsorted_kernel, dim3((n + 255) / 256), dim3(256), 0, stream,
                           pts, cp, out, n);
    }
}

// Round 6
// 167.493 us; speedup vs baseline: 4.3795x; 1.4611x over previous
//
#include <hip/hip_runtime.h>

#define GRID_DIM 132
#define SLAB (GRID_DIM * GRID_DIM)   // 17424
#define NB 512                       // 8x8x8 bins, each 16^3 in int(t) space
#define CHUNK 2048                   // points per partition block
#define KPT (CHUNK / 256)            // 8 points per thread
#define REG 20                       // staged region edge (16 + 3 taps + 1 slack)
#define REG3 (REG * REG * REG)       // 8000 floats = 32 KB
#define STRIPE 8192                  // entries per scan_l1 block

__device__ __forceinline__ void bspline_w(float x, float w[4]) {
    float omx = 1.0f - x;
    w[0] = omx * omx * omx * (1.0f / 6.0f);
    w[1] = (3.0f * (x - 2.0f) * x * x + 4.0f) * (1.0f / 6.0f);
    w[2] = (-3.0f * omx * omx * (x + 1.0f) + 4.0f) * (1.0f / 6.0f);
    w[3] = x * x * x * (1.0f / 6.0f);
}

__device__ __forceinline__ void load_pt(const float* __restrict__ pts, int i,
                                        float& tx, float& ty, float& tz, bool& inb) {
    tx = pts[3 * i + 0] + 1.0f;   // ORIGIN = -(1+1e-8) == -1.0f in fp32, STEP = 1
    ty = pts[3 * i + 1] + 1.0f;
    tz = pts[3 * i + 2] + 1.0f;
    inb = (tx >= 1.0f) && (ty >= 1.0f) && (tz >= 1.0f) &&
          (tx < 130.0f) && (ty < 130.0f) && (tz < 130.0f);
    if (!inb) { tx = ty = tz = 1.0f; }
}

// 512-bin id, x-major (round-2/4 proven form)
__device__ __forceinline__ int calc_bin(float tx, float ty, float tz) {
    int bx = min(7, ((int)tx - 1) >> 4);
    int by = min(7, ((int)ty - 1) >> 4);
    int bz = min(7, ((int)tz - 1) >> 4);
    return (bx << 6) | (by << 3) | bz;
}

// Per-chunk 512-bin histogram -> bh[bin*nblk + blk] (bin-major). No global atomics.
__global__ __launch_bounds__(256) void hist512_kernel(
    const float* __restrict__ pts, int n, int nblk, unsigned* __restrict__ bh)
{
    __shared__ unsigned lh[NB];
    int tid = threadIdx.x, blk = blockIdx.x;
    int c0 = blk * CHUNK;
    for (int b = tid; b < NB; b += 256) lh[b] = 0u;
    __syncthreads();
#pragma unroll
    for (int k = 0; k < KPT; ++k) {
        int i = c0 + tid + k * 256;
        if (i < n) {
            float tx, ty, tz; bool inb;
            load_pt(pts, i, tx, ty, tz, inb);
            atomicAdd(&lh[calc_bin(tx, ty, tz)], 1u);
        }
    }
    __syncthreads();
    for (int b = tid; b < NB; b += 256) bh[b * nblk + blk] = lh[b];
}

// Stripe-local exclusive scan (8192 entries/block) + stripe totals.
__global__ __launch_bounds__(256) void scan_l1_kernel(
    const unsigned* __restrict__ bh, unsigned* __restrict__ seg,
    unsigned* __restrict__ stot, int TOT)
{
    __shared__ unsigned sc[256];
    int t = threadIdx.x;
    int base_idx = blockIdx.x * STRIPE + t * 32;
    unsigned local[32];
    unsigned s = 0;
#pragma unroll
    for (int j = 0; j < 32; ++j) {
        int idx = base_idx + j;
        unsigned v = (idx < TOT) ? bh[idx] : 0u;
        local[j] = v; s += v;
    }
    sc[t] = s;
    __syncthreads();
    for (int off = 1; off < 256; off <<= 1) {
        unsigned v = (t >= off) ? sc[t - off] : 0u;
        __syncthreads();
        sc[t] += v;
        __syncthreads();
    }
    unsigned run = (t == 0) ? 0u : sc[t - 1];
#pragma unroll
    for (int j = 0; j < 32; ++j) {
        int idx = base_idx + j;
        if (idx < TOT) seg[idx] = run;
        run += local[j];
    }
    if (t == 255) stot[blockIdx.x] = sc[255];
}

// Exclusive scan of stripe totals (<=256 stripes), one block.
__global__ __launch_bounds__(256) void scan_l2_kernel(
    const unsigned* __restrict__ stot, unsigned* __restrict__ soff, int nstripe)
{
    __shared__ unsigned sc[256];
    int t = threadIdx.x;
    sc[t] = (t < nstripe) ? stot[t] : 0u;
    __syncthreads();
    for (int off = 1; off < 256; off <<= 1) {
        unsigned u = (t >= off) ? sc[t - off] : 0u;
        __syncthreads();
        sc[t] += u;
        __syncthreads();
    }
    if (t < nstripe) soff[t] = (t == 0) ? 0u : sc[t - 1];
}

// Add stripe offsets: seg[idx] += soff[stripe(idx)].
__global__ __launch_bounds__(256) void scan_l3_kernel(
    unsigned* __restrict__ seg, const unsigned* __restrict__ soff, int TOT)
{
    int idx = blockIdx.x * 256 + threadIdx.x;
    if (idx < TOT) seg[idx] += soff[blockIdx.x / (STRIPE / 256)];
}

// Deterministic 512-way partition (round-5 proven structure, NB=512):
// points in registers, LDS-ordered by bin, contiguous per-(block,bin) runs,
// inv[] writes confined to the chunk's 8KB window. No global atomics.
__global__ __launch_bounds__(256) void partition_kernel(
    const float* __restrict__ pts, int n, int nblk,
    const unsigned* __restrict__ segstart,
    float4* __restrict__ sorted, unsigned* __restrict__ inv)
{
    __shared__ float4 buf[CHUNK];                       // 32 KB
    __shared__ unsigned lcnt[NB], lstart[NB], lcur[NB], gseg[NB];  // 8 KB
    __shared__ unsigned sc[256];                        // 1 KB
    int tid = threadIdx.x, blk = blockIdx.x;
    int c0 = blk * CHUNK;
    int m = min(n - c0, CHUNK);

    for (int b = tid; b < NB; b += 256) lcnt[b] = 0u;
    __syncthreads();

    float4 pv[KPT];
    int bins[KPT];
#pragma unroll
    for (int k = 0; k < KPT; ++k) {
        int i = c0 + tid + k * 256;
        bins[k] = -1;
        if (i < n) {
            float tx, ty, tz; bool inb;
            load_pt(pts, i, tx, ty, tz, inb);
            unsigned tag = (unsigned)i | (inb ? 0u : 0x80000000u);
            pv[k] = make_float4(tx, ty, tz, __uint_as_float(tag));
            bins[k] = calc_bin(tx, ty, tz);
            atomicAdd(&lcnt[bins[k]], 1u);
        }
    }
    __syncthreads();

    // exclusive scan of lcnt[512], 2 bins/thread (proven scan_kernel pattern)
    unsigned a = lcnt[2 * tid], b2 = lcnt[2 * tid + 1];
    sc[tid] = a + b2;
    __syncthreads();
    for (int off = 1; off < 256; off <<= 1) {
        unsigned v = (tid >= off) ? sc[tid - off] : 0u;
        __syncthreads();
        sc[tid] += v;
        __syncthreads();
    }
    unsigned base = (tid == 0) ? 0u : sc[tid - 1];
    lstart[2 * tid] = base;
    lstart[2 * tid + 1] = base + a;
    __syncthreads();
    for (int b = tid; b < NB; b += 256) {
        lcur[b] = lstart[b];
        gseg[b] = segstart[b * nblk + blk];
    }
    __syncthreads();

#pragma unroll
    for (int k = 0; k < KPT; ++k) {
        if (bins[k] >= 0) {
            unsigned pos = atomicAdd(&lcur[bins[k]], 1u);
            buf[pos] = pv[k];
        }
    }
    __syncthreads();

    for (int j = tid; j < m; j += 256) {
        float4 p = buf[j];
        int b = calc_bin(p.x, p.y, p.z);
        unsigned g = gseg[b] + ((unsigned)j - lstart[b]);
        sorted[g] = p;
        inv[__float_as_uint(p.w) & 0x7fffffffu] = g;
    }
}

// One block per (bin, half): stage bin's 20^3 region in LDS (random taps hit
// 32 banks in parallel -- beats the TA's per-line serialization), write val_s
// dense by sorted position. XCD swizzle: each XCD owns one x-slab (1.4MB in L2).
__global__ __launch_bounds__(256) void eval_kernel(
    const float4* __restrict__ sorted, const float* __restrict__ cp,
    const unsigned* __restrict__ segstart, float* __restrict__ val_s,
    int n, int nblk)
{
    __shared__ float region[REG3];   // 32 KB

    int bid = blockIdx.x;
    int wg = (bid & 7) * 128 + (bid >> 3);   // proven r4 swizzle, 1024 blocks
    int bin = wg >> 1, half = wg & 1;
    int x0 = (bin >> 6) << 4, y0 = ((bin >> 3) & 7) << 4, z0 = (bin & 7) << 4;

    const float* src = cp + (size_t)x0 * SLAB + y0 * GRID_DIM + z0;
    for (int v = threadIdx.x; v < REG3; v += 256) {
        int gx = v / (REG * REG);
        int r = v - gx * (REG * REG);
        int gy = r / REG;
        int gz = r - gy * REG;
        region[v] = src[gx * SLAB + gy * GRID_DIM + gz];
    }
    __syncthreads();

    unsigned s = segstart[bin * nblk];
    unsigned e = (bin == NB - 1) ? (unsigned)n : segstart[(bin + 1) * nblk];
    unsigned hlen = (e - s) >> 1;
    unsigned i0 = s + hlen * half;
    unsigned i1 = half ? e : s + hlen;

    for (unsigned i = i0 + threadIdx.x; i < i1; i += 256) {
        float4 p = sorted[i];
        unsigned tag = __float_as_uint(p.w);
        int ix = (int)p.x, iy = (int)p.y, iz = (int)p.z;
        float wx[4], wy[4], wz[4];
        bspline_w(p.x - (float)ix, wx);
        bspline_w(p.y - (float)iy, wy);
        bspline_w(p.z - (float)iz, wz);
        int lx = ix - 1 - x0, ly = iy - 1 - y0, lz = iz - 1 - z0;
        const float* rb = region + (lx * REG + ly) * REG + lz;
        float acc = 0.0f;
#pragma unroll
        for (int a = 0; a < 4; ++a) {
            float accy = 0.0f;
#pragma unroll
            for (int b = 0; b < 4; ++b) {
                const float* row = rb + (a * REG + b) * REG;
                float sz = fmaf(row[0], wz[0], fmaf(row[1], wz[1],
                           fmaf(row[2], wz[2], row[3] * wz[3])));
                accy = fmaf(wy[b], sz, accy);
            }
            acc = fmaf(wx[a], accy, acc);
        }
        val_s[i] = (tag >> 31) ? 0.0f : acc;
    }
}

// out[i] = val_s[inv[i]] : dense inv reads, random 4B READS of cached val_s,
// dense out writes. (Proven rounds 4/5.)
__global__ __launch_bounds__(256) void unscatter_kernel(
    const float* __restrict__ val_s, const unsigned* __restrict__ inv,
    float* __restrict__ out, int n)
{
    int g = blockIdx.x * blockDim.x + threadIdx.x;
    int base = g * 4;
    if (base + 3 < n) {
        uint4 iv = ((const uint4*)inv)[g];
        float4 o;
        o.x = val_s[iv.x]; o.y = val_s[iv.y]; o.z = val_s[iv.z]; o.w = val_s[iv.w];
        ((float4*)out)[g] = o;
    } else if (base < n) {
        for (int k = base; k < n; ++k) out[k] = val_s[inv[k]];
    }
}

// Fallback (round-1 proven) if ws/config insufficient.
__global__ __launch_bounds__(256) void eval_unsorted_kernel(
    const float* __restrict__ pts, const float* __restrict__ cp,
    float* __restrict__ out, int n)
{
    int i = blockIdx.x * blockDim.x + threadIdx.x;
    if (i >= n) return;
    float tx, ty, tz; bool inb;
    load_pt(pts, i, tx, ty, tz, inb);
    int ix = (int)tx, iy = (int)ty, iz = (int)tz;
    float wx[4], wy[4], wz[4];
    bspline_w(tx - (float)ix, wx);
    bspline_w(ty - (float)iy, wy);
    bspline_w(tz - (float)iz, wz);
    const float* bse = cp + (size_t)(ix - 1) * SLAB + (size_t)(iy - 1) * GRID_DIM + (iz - 1);
    float acc = 0.0f;
#pragma unroll
    for (int a = 0; a < 4; ++a) {
        float accy = 0.0f;
#pragma unroll
        for (int b = 0; b < 4; ++b) {
            const float* row = bse + a * SLAB + b * GRID_DIM;
            float4 v;
            __builtin_memcpy(&v, row, 16);
            float sz = fmaf(v.x, wz[0], fmaf(v.y, wz[1], fmaf(v.z, wz[2], v.w * wz[3])));
            accy = fmaf(wy[b], sz, accy);
        }
        acc = fmaf(wx[a], accy, acc);
    }
    out[i] = inb ? acc : 0.0f;
}

extern "C" void kernel_launch(void* const* d_in, const int* in_sizes, int n_in,
                              void* d_out, int out_size, void* d_ws, size_t ws_size,
                              hipStream_t stream) {
    const float* pts = (const float*)d_in[0];      // (N, 3) fp32
    const float* cp  = (const float*)d_in[1];      // (1, 132, 132, 132) fp32
    float* out       = (float*)d_out;              // (N, 1) fp32

    int n = in_sizes[0] / 3;                       // 2,000,000
    int nblk = (n + CHUNK - 1) / CHUNK;            // 977
    int TOT = NB * nblk;                           // 500,224
    int nstripe = (TOT + STRIPE - 1) / STRIPE;     // 62

    // ws layout (all fully rewritten every call; no memsets needed):
    // bh[TOT] | seg[TOT] | stot[256] | soff[256] | sorted f4[n] | inv u32[n] | val_s f32[n]
    size_t A          = (((size_t)TOT * 4) + 1023) & ~(size_t)1023;
    size_t off_seg    = A;
    size_t off_stot   = 2 * A;
    size_t off_soff   = 2 * A + 1024;
    size_t off_sorted = 2 * A + 2048;
    size_t off_inv    = off_sorted + (size_t)n * sizeof(float4);
    size_t off_val    = off_inv    + (size_t)n * sizeof(unsigned);
    size_t need       = off_val    + (size_t)n * sizeof(float);

    if (ws_size >= need && nblk <= 1024 && nstripe <= 256) {
        unsigned* bh     = (unsigned*)d_ws;
        unsigned* seg    = (unsigned*)((char*)d_ws + off_seg);
        unsigned* stot   = (unsigned*)((char*)d_ws + off_stot);
        unsigned* soff   = (unsigned*)((char*)d_ws + off_soff);
        float4*   sorted = (float4*)((char*)d_ws + off_sorted);
        unsigned* inv    = (unsigned*)((char*)d_ws + off_inv);
        float*    val_s  = (float*)((char*)d_ws + off_val);

        int uwg = ((n + 3) / 4 + 255) / 256;

        hipLaunchKernelGGL(hist512_kernel, dim3(nblk), dim3(256), 0, stream,
                           pts, n, nblk, bh);
        hipLaunchKernelGGL(scan_l1_kernel, dim3(nstripe), dim3(256), 0, stream,
                           bh, seg, stot, TOT);
        hipLaunchKernelGGL(scan_l2_kernel, dim3(1), dim3(256), 0, stream,
                           stot, soff, nstripe);
        hipLaunchKernelGGL(scan_l3_kernel, dim3((TOT + 255) / 256), dim3(256), 0, stream,
                           seg, soff, TOT);
        hipLaunchKernelGGL(partition_kernel, dim3(nblk), dim3(256), 0, stream,
                           pts, n, nblk, seg, sorted, inv);
        hipLaunchKernelGGL(eval_kernel, dim3(1024), dim3(256), 0, stream,
                           sorted, cp, seg, val_s, n, nblk);
        hipLaunchKernelGGL(unscatter_kernel, dim3(uwg), dim3(256), 0, stream,
                           val_s, inv, out, n);
    } else {
        hipLaunchKernelGGL(eval_unsorted_kernel, dim3((n + 255) / 256), dim3(256), 0, stream,
                           pts, cp, out, n);
    }
}

// Round 7
// 166.184 us; speedup vs baseline: 4.4140x; 1.0079x over previous
//
#include <hip/hip_runtime.h>

#define GRID_DIM 132
#define SLAB (GRID_DIM * GRID_DIM)   // 17424
#define NB 512                       // 8x8x8 bins, each 16^3 in int(t) space
#define CHUNK 2048                   // points per partition block
#define KPT (CHUNK / 256)            // 8 points per thread
#define REG 20                       // staged region edge (17-wide edge bin + 3 taps)
#define REG2 (REG * REG)
#define REG3 (REG * REG * REG)       // 8000 floats = 32 KB
#define STRIPE 8192                  // entries per scan_l1 block (2^13)

__device__ __forceinline__ void bspline_w(float x, float w[4]) {
    float omx = 1.0f - x;
    w[0] = omx * omx * omx * (1.0f / 6.0f);
    w[1] = (3.0f * (x - 2.0f) * x * x + 4.0f) * (1.0f / 6.0f);
    w[2] = (-3.0f * omx * omx * (x + 1.0f) + 4.0f) * (1.0f / 6.0f);
    w[3] = x * x * x * (1.0f / 6.0f);
}

__device__ __forceinline__ void load_pt(const float* __restrict__ pts, int i,
                                        float& tx, float& ty, float& tz, bool& inb) {
    tx = pts[3 * i + 0] + 1.0f;   // ORIGIN = -(1+1e-8) == -1.0f in fp32, STEP = 1
    ty = pts[3 * i + 1] + 1.0f;
    tz = pts[3 * i + 2] + 1.0f;
    inb = (tx >= 1.0f) && (ty >= 1.0f) && (tz >= 1.0f) &&
          (tx < 130.0f) && (ty < 130.0f) && (tz < 130.0f);
    if (!inb) { tx = ty = tz = 1.0f; }
}

// 512-bin id, x-major (proven)
__device__ __forceinline__ int calc_bin(float tx, float ty, float tz) {
    int bx = min(7, ((int)tx - 1) >> 4);
    int by = min(7, ((int)ty - 1) >> 4);
    int bz = min(7, ((int)tz - 1) >> 4);
    return (bx << 6) | (by << 3) | bz;
}

// In-LDS exclusive scan of stripe totals (<=256). Barriers unconditional:
// safe for any blockDim >= 256.
__device__ __forceinline__ void local_stripe_scan(
    const unsigned* __restrict__ stot, int nstripe,
    unsigned* soff, unsigned* sc)
{
    int t = threadIdx.x;
    if (t < 256) sc[t] = (t < nstripe) ? stot[t] : 0u;
    __syncthreads();
    for (int off = 1; off < 256; off <<= 1) {
        unsigned v = (t >= off && t < 256) ? sc[t - off] : 0u;
        __syncthreads();
        if (t < 256) sc[t] += v;
        __syncthreads();
    }
    if (t < 256) soff[t] = (t == 0) ? 0u : sc[t - 1];
    __syncthreads();
}

// Per-chunk 512-bin histogram -> bh[bin*nblk + blk] (bin-major). No global atomics.
__global__ __launch_bounds__(256) void hist512_kernel(
    const float* __restrict__ pts, int n, int nblk, unsigned* __restrict__ bh)
{
    __shared__ unsigned lh[NB];
    int tid = threadIdx.x, blk = blockIdx.x;
    int c0 = blk * CHUNK;
    for (int b = tid; b < NB; b += 256) lh[b] = 0u;
    __syncthreads();
#pragma unroll
    for (int k = 0; k < KPT; ++k) {
        int i = c0 + tid + k * 256;
        if (i < n) {
            float tx, ty, tz; bool inb;
            load_pt(pts, i, tx, ty, tz, inb);
            atomicAdd(&lh[calc_bin(tx, ty, tz)], 1u);
        }
    }
    __syncthreads();
    for (int b = tid; b < NB; b += 256) bh[b * nblk + blk] = lh[b];
}

// Stripe-local exclusive scan (8192 entries/block) + stripe totals.
__global__ __launch_bounds__(256) void scan_l1_kernel(
    const unsigned* __restrict__ bh, unsigned* __restrict__ seg,
    unsigned* __restrict__ stot, int TOT)
{
    __shared__ unsigned sc[256];
    int t = threadIdx.x;
    int base_idx = blockIdx.x * STRIPE + t * 32;
    unsigned local[32];
    unsigned s = 0;
#pragma unroll
    for (int j = 0; j < 32; ++j) {
        int idx = base_idx + j;
        unsigned v = (idx < TOT) ? bh[idx] : 0u;
        local[j] = v; s += v;
    }
    sc[t] = s;
    __syncthreads();
    for (int off = 1; off < 256; off <<= 1) {
        unsigned v = (t >= off) ? sc[t - off] : 0u;
        __syncthreads();
        sc[t] += v;
        __syncthreads();
    }
    unsigned run = (t == 0) ? 0u : sc[t - 1];
#pragma unroll
    for (int j = 0; j < 32; ++j) {
        int idx = base_idx + j;
        if (idx < TOT) seg[idx] = run;
        run += local[j];
    }
    if (t == 255) stot[blockIdx.x] = sc[255];
}

// Deterministic 512-way partition (r6-proven structure) + XCD-bijective chunk
// swizzle: consecutive chunks (which write ADJACENT 64B runs in every bin
// segment) run on the SAME XCD so its L2 assembles full lines before writeback.
__global__ __launch_bounds__(256) void partition_kernel(
    const float* __restrict__ pts, int n, int nblk,
    const unsigned* __restrict__ seg, const unsigned* __restrict__ stot,
    int nstripe, float4* __restrict__ sorted, unsigned* __restrict__ inv)
{
    __shared__ float4 buf[CHUNK];                       // 32 KB
    __shared__ unsigned lcnt[NB], lstart[NB], lcur[NB], gseg[NB];  // 8 KB
    __shared__ unsigned sc[256], soff[256];             // 2 KB

    local_stripe_scan(stot, nstripe, soff, sc);

    // bijective XCD swizzle (m204): XCD j owns contiguous chunk range
    int bid = blockIdx.x;
    int q = nblk >> 3, r = nblk & 7;
    int xcd = bid & 7, pos = bid >> 3;
    int blk = (xcd < r ? xcd * (q + 1) : r * (q + 1) + (xcd - r) * q) + pos;

    int tid = threadIdx.x;
    int c0 = blk * CHUNK;
    int m = min(n - c0, CHUNK);

    for (int b = tid; b < NB; b += 256) lcnt[b] = 0u;
    __syncthreads();

    float4 pv[KPT];
    int bins[KPT];
#pragma unroll
    for (int k = 0; k < KPT; ++k) {
        int i = c0 + tid + k * 256;
        bins[k] = -1;
        if (i < n && i < c0 + CHUNK) {
            float tx, ty, tz; bool inb;
            load_pt(pts, i, tx, ty, tz, inb);
            unsigned tag = (unsigned)i | (inb ? 0u : 0x80000000u);
            pv[k] = make_float4(tx, ty, tz, __uint_as_float(tag));
            bins[k] = calc_bin(tx, ty, tz);
            atomicAdd(&lcnt[bins[k]], 1u);
        }
    }
    __syncthreads();

    // exclusive scan of lcnt[512], 2 bins/thread (proven pattern)
    unsigned a = lcnt[2 * tid], b2 = lcnt[2 * tid + 1];
    sc[tid] = a + b2;
    __syncthreads();
    for (int off = 1; off < 256; off <<= 1) {
        unsigned v = (tid >= off) ? sc[tid - off] : 0u;
        __syncthreads();
        sc[tid] += v;
        __syncthreads();
    }
    unsigned base = (tid == 0) ? 0u : sc[tid - 1];
    lstart[2 * tid] = base;
    lstart[2 * tid + 1] = base + a;
    __syncthreads();
    for (int b = tid; b < NB; b += 256) {
        lcur[b] = lstart[b];
        int idx = b * nblk + blk;
        gseg[b] = seg[idx] + soff[idx >> 13];           // STRIPE = 2^13
    }
    __syncthreads();

#pragma unroll
    for (int k = 0; k < KPT; ++k) {
        if (bins[k] >= 0) {
            unsigned p2 = atomicAdd(&lcur[bins[k]], 1u);
            buf[p2] = pv[k];
        }
    }
    __syncthreads();

    for (int j = tid; j < m; j += 256) {
        float4 p = buf[j];
        int b = calc_bin(p.x, p.y, p.z);
        unsigned g = gseg[b] + ((unsigned)j - lstart[b]);
        sorted[g] = p;
        inv[__float_as_uint(p.w) & 0x7fffffffu] = g;   // chunk-local dense window
    }
}

// One 512-thread block per bin: stage the bin's 20^3 region in LDS ONCE,
// evaluate its points (random taps hit 32 banks in parallel), write val_s
// dense by sorted position. bin = (bid&7)*64 + bid>>3 pins each XCD to one
// x-slab (region reads stay in its L2).
__global__ __launch_bounds__(512) void eval_kernel(
    const float4* __restrict__ sorted, const float* __restrict__ cp,
    const unsigned* __restrict__ seg, const unsigned* __restrict__ stot,
    int nstripe, float* __restrict__ val_s, int n, int nblk)
{
    __shared__ float region[REG3];   // 32 KB
    __shared__ unsigned sc[256], soff[256];

    local_stripe_scan(stot, nstripe, soff, sc);

    int bid = blockIdx.x;
    int bin = (bid & 7) * 64 + (bid >> 3);   // 512 = 8 XCDs x 64 bins
    int x0 = (bin >> 6) << 4, y0 = ((bin >> 3) & 7) << 4, z0 = (bin & 7) << 4;

    const float* src = cp + (size_t)x0 * SLAB + y0 * GRID_DIM + z0;
    for (int v = threadIdx.x; v < REG3; v += 512) {
        int gx = v / REG2;
        int rr = v - gx * REG2;
        int gy = rr / REG;
        int gz = rr - gy * REG;
        region[v] = src[gx * SLAB + gy * GRID_DIM + gz];
    }
    __syncthreads();

    int i0 = bin * nblk;
    unsigned s = seg[i0] + soff[i0 >> 13];
    unsigned e;
    if (bin == NB - 1) e = (unsigned)n;
    else { int i1 = (bin + 1) * nblk; e = seg[i1] + soff[i1 >> 13]; }

    for (unsigned i = s + threadIdx.x; i < e; i += 512) {
        float4 p = sorted[i];
        unsigned tag = __float_as_uint(p.w);
        int ix = (int)p.x, iy = (int)p.y, iz = (int)p.z;
        float wx[4], wy[4], wz[4];
        bspline_w(p.x - (float)ix, wx);
        bspline_w(p.y - (float)iy, wy);
        bspline_w(p.z - (float)iz, wz);
        int lx = ix - 1 - x0, ly = iy - 1 - y0, lz = iz - 1 - z0;
        const float* rb = region + (lx * REG + ly) * REG + lz;
        float acc = 0.0f;
#pragma unroll
        for (int a = 0; a < 4; ++a) {
            float accy = 0.0f;
#pragma unroll
            for (int b = 0; b < 4; ++b) {
                const float* row = rb + (a * REG + b) * REG;
                float sz = fmaf(row[0], wz[0], fmaf(row[1], wz[1],
                           fmaf(row[2], wz[2], row[3] * wz[3])));
                accy = fmaf(wy[b], sz, accy);
            }
            acc = fmaf(wx[a], accy, acc);
        }
        val_s[i] = (tag >> 31) ? 0.0f : acc;
    }
}

// out[i] = val_s[inv[i]] : dense inv reads, random 4B READS of cached val_s,
// dense out writes. (Proven rounds 4-6.)
__global__ __launch_bounds__(256) void unscatter_kernel(
    const float* __restrict__ val_s, const unsigned* __restrict__ inv,
    float* __restrict__ out, int n)
{
    int g = blockIdx.x * blockDim.x + threadIdx.x;
    int base = g * 4;
    if (base + 3 < n) {
        uint4 iv = ((const uint4*)inv)[g];
        float4 o;
        o.x = val_s[iv.x]; o.y = val_s[iv.y]; o.z = val_s[iv.z]; o.w = val_s[iv.w];
        ((float4*)out)[g] = o;
    } else if (base < n) {
        for (int k = base; k < n; ++k) out[k] = val_s[inv[k]];
    }
}

// Fallback (round-1 proven) if ws/config insufficient.
__global__ __launch_bounds__(256) void eval_unsorted_kernel(
    const float* __restrict__ pts, const float* __restrict__ cp,
    float* __restrict__ out, int n)
{
    int i = blockIdx.x * blockDim.x + threadIdx.x;
    if (i >= n) return;
    float tx, ty, tz; bool inb;
    load_pt(pts, i, tx, ty, tz, inb);
    int ix = (int)tx, iy = (int)ty, iz = (int)tz;
    float wx[4], wy[4], wz[4];
    bspline_w(tx - (float)ix, wx);
    bspline_w(ty - (float)iy, wy);
    bspline_w(tz - (float)iz, wz);
    const float* bse = cp + (size_t)(ix - 1) * SLAB + (size_t)(iy - 1) * GRID_DIM + (iz - 1);
    float acc = 0.0f;
#pragma unroll
    for (int a = 0; a < 4; ++a) {
        float accy = 0.0f;
#pragma unroll
        for (int b = 0; b < 4; ++b) {
            const float* row = bse + a * SLAB + b * GRID_DIM;
            float4 v;
            __builtin_memcpy(&v, row, 16);
            float sz = fmaf(v.x, wz[0], fmaf(v.y, wz[1], fmaf(v.z, wz[2], v.w * wz[3])));
            accy = fmaf(wy[b], sz, accy);
        }
        acc = fmaf(wx[a], accy, acc);
    }
    out[i] = inb ? acc : 0.0f;
}

extern "C" void kernel_launch(void* const* d_in, const int* in_sizes, int n_in,
                              void* d_out, int out_size, void* d_ws, size_t ws_size,
                              hipStream_t stream) {
    const float* pts = (const float*)d_in[0];      // (N, 3) fp32
    const float* cp  = (const float*)d_in[1];      // (1, 132, 132, 132) fp32
    float* out       = (float*)d_out;              // (N, 1) fp32

    int n = in_sizes[0] / 3;                       // 2,000,000
    int nblk = (n + CHUNK - 1) / CHUNK;            // 977
    int TOT = NB * nblk;                           // 500,224
    int nstripe = (TOT + STRIPE - 1) / STRIPE;     // 62

    // ws layout (all fully rewritten every call; no memsets needed):
    // bh[TOT] | seg[TOT] | stot[256] | sorted f4[n] | inv u32[n] | val_s f32[n]
    size_t A          = (((size_t)TOT * 4) + 1023) & ~(size_t)1023;
    size_t off_seg    = A;
    size_t off_stot   = 2 * A;
    size_t off_sorted = 2 * A + 1024;
    size_t off_inv    = off_sorted + (size_t)n * sizeof(float4);
    size_t off_val    = off_inv    + (size_t)n * sizeof(unsigned);
    size_t need       = off_val    + (size_t)n * sizeof(float);

    if (ws_size >= need && nblk <= 1024 && nstripe <= 256) {
        unsigned* bh     = (unsigned*)d_ws;
        unsigned* seg    = (unsigned*)((char*)d_ws + off_seg);
        unsigned* stot   = (unsigned*)((char*)d_ws + off_stot);
        float4*   sorted = (float4*)((char*)d_ws + off_sorted);
        unsigned* inv    = (unsigned*)((char*)d_ws + off_inv);
        float*    val_s  = (float*)((char*)d_ws + off_val);

        int uwg = ((n + 3) / 4 + 255) / 256;

        hipLaunchKernelGGL(hist512_kernel, dim3(nblk), dim3(256), 0, stream,
                           pts, n, nblk, bh);
        hipLaunchKernelGGL(scan_l1_kernel, dim3(nstripe), dim3(256), 0, stream,
                           bh, seg, stot, TOT);
        hipLaunchKernelGGL(partition_kernel, dim3(nblk), dim3(256), 0, stream,
                           pts, n, nblk, seg, stot, nstripe, sorted, inv);
        hipLaunchKernelGGL(eval_kernel, dim3(NB), dim3(512), 0, stream,
                           sorted, cp, seg, stot, nstripe, val_s, n, nblk);
        hipLaunchKernelGGL(unscatter_kernel, dim3(uwg), dim3(256), 0, stream,
                           val_s, inv, out, n);
    } else {
        hipLaunchKernelGGL(eval_unsorted_kernel, dim3((n + 255) / 256), dim3(256), 0, stream,
                           pts, cp, out, n);
    }
}